// Round 1
// baseline (103.507 us; speedup 1.0000x reference)
//
#include <hip/hip_runtime.h>
#include <hip/hip_bf16.h>

// HardAttention: out = tanh([context|output] @ W^T + b)  (GEMM M=16384,K=1024,N=512, bf16 MFMA)
//                attn = constant one-hot [4,4096,4096]   (256 MiB write-bound fill)
// Fused single kernel: blocks [0,512) do GEMM tiles, blocks [512,2048) do the fill,
// so the HBM store stream overlaps the MFMA work.

typedef __attribute__((ext_vector_type(8))) short bf16x8;   // 8 bf16 = 4 VGPRs
typedef __attribute__((ext_vector_type(4))) float f32x4;

#define B_N 4
#define L_N 4096
#define S_N 4096
#define D_N 512
#define M_N (B_N * L_N)   // 16384
#define K_N (2 * D_N)     // 1024

#define BM 128
#define BN 128
#define GEMM_BLOCKS ((M_N / BM) * (D_N / BN))  // 128 * 4 = 512
#define FILL_BLOCKS 1536
#define NTHREADS 256

static __device__ __forceinline__ short f2bf(float f) {
  unsigned u = __builtin_bit_cast(unsigned, f);
  u += 0x7fffu + ((u >> 16) & 1u);   // RNE
  return (short)(u >> 16);
}

static __device__ __forceinline__ bf16x8 pack8(f32x4 a, f32x4 b) {
  bf16x8 r;
  r[0] = f2bf(a.x); r[1] = f2bf(a.y); r[2] = f2bf(a.z); r[3] = f2bf(a.w);
  r[4] = f2bf(b.x); r[5] = f2bf(b.y); r[6] = f2bf(b.z); r[7] = f2bf(b.w);
  return r;
}

__global__ __launch_bounds__(NTHREADS, 2)
void hardattn_fused(const float* __restrict__ outp,   // [B,L,D] "output"
                    const float* __restrict__ ctx,    // [B,S,D] "context"
                    const float* __restrict__ W,      // [D, 2D] row-major = [N=512][K=1024]
                    const float* __restrict__ bias,   // [D]
                    float* __restrict__ dout)         // out [M,512] then attn [B,L,S]
{
  // LDS tiles: 128 rows x 64 bf16 (128 B per row), XOR-swizzled (G4)
  __shared__ char As[128 * 128];
  __shared__ char Bs[128 * 128];

  const int bid = blockIdx.x;
  const int tid = threadIdx.x;

  if (bid >= GEMM_BLOCKS) {
    // ---------------- attn fill: 256 MiB one-hot ----------------
    float* attn = dout + (size_t)M_N * D_N;          // offset 8,388,608 floats
    const int total4 = (B_N * L_N * (S_N / 4));      // 16,777,216 float4s
    const int stride = FILL_BLOCKS * NTHREADS;
    for (int i = (bid - GEMM_BLOCKS) * NTHREADS + tid; i < total4; i += stride) {
      const int f = i << 2;                          // flat float index < 2^26
      const int col = f & (S_N - 1);
      const int l   = (f >> 12) & (L_N - 1);
      f32x4 v;
      v.x = (col     == l) ? 1.0f : 0.0f;
      v.y = (col + 1 == l) ? 1.0f : 0.0f;
      v.z = (col + 2 == l) ? 1.0f : 0.0f;
      v.w = (col + 3 == l) ? 1.0f : 0.0f;
      __builtin_nontemporal_store(v, (f32x4*)attn + i);  // don't pollute L2/L3
    }
    return;
  }

  // ---------------- GEMM: out = tanh(A @ W^T + b) ----------------
  // A[m,k] = (k<512) ? ctx[m*512+k] : outp[m*512+k-512]   (m = b*4096+l)
  const int mt = bid >> 2;            // 4 consecutive blocks share the A panel
  const int nt = bid & 3;
  const int row0 = mt * BM;
  const int col0 = nt * BN;
  const int lane = tid & 63;
  const int wid  = tid >> 6;
  const int wr = (wid >> 1) * 64;     // wave 64x64 sub-tile
  const int wc = (wid & 1) * 64;

  f32x4 acc[4][4] = {};

  // staging: thread -> row sr (0..127), half sh (cols [sh,sh+32) of the 64-col tile)
  const int sr = tid >> 1;
  const int sh = (tid & 1) * 32;
  const float* bRowW = W + (size_t)(col0 + sr) * K_N;

  for (int kt = 0; kt < 16; ++kt) {
    const float* ap = ((kt < 8) ? ctx : outp) + (size_t)(row0 + sr) * D_N + ((kt & 7) * 64 + sh);
    const float* bp = bRowW + (kt * 64 + sh);
    f32x4 a4[8], b4[8];
#pragma unroll
    for (int q = 0; q < 8; ++q) a4[q] = ((const f32x4*)ap)[q];
#pragma unroll
    for (int q = 0; q < 8; ++q) b4[q] = ((const f32x4*)bp)[q];
    bf16x8 pa[4], pb[4];
#pragma unroll
    for (int q = 0; q < 4; ++q) {
      pa[q] = pack8(a4[2 * q], a4[2 * q + 1]);
      pb[q] = pack8(b4[2 * q], b4[2 * q + 1]);
    }
    __syncthreads();   // previous tile's reads done
    {
      const int wbase = sr * 128;
      const int wswz  = (sr & 7) << 4;
#pragma unroll
      for (int q = 0; q < 4; ++q) {
        const int kb = sh * 2 + q * 16;          // byte offset within 128B row
        *(bf16x8*)&As[wbase + (kb ^ wswz)] = pa[q];
        *(bf16x8*)&Bs[wbase + (kb ^ wswz)] = pb[q];
      }
    }
    __syncthreads();   // tile ready

#pragma unroll
    for (int kk = 0; kk < 2; ++kk) {
      const int kb = kk * 64 + ((lane >> 4) << 4);
      bf16x8 af[4], bfr[4];
#pragma unroll
      for (int i = 0; i < 4; ++i) {
        const int ar = wr + i * 16 + (lane & 15);
        af[i]  = *(const bf16x8*)&As[ar * 128 + (kb ^ ((ar & 7) << 4))];
        const int br = wc + i * 16 + (lane & 15);
        bfr[i] = *(const bf16x8*)&Bs[br * 128 + (kb ^ ((br & 7) << 4))];
      }
#pragma unroll
      for (int i = 0; i < 4; ++i)
#pragma unroll
        for (int j = 0; j < 4; ++j)
          acc[i][j] = __builtin_amdgcn_mfma_f32_16x16x32_bf16(af[i], bfr[j], acc[i][j], 0, 0, 0);
    }
  }

  // epilogue: C/D layout col=lane&15, row=(lane>>4)*4+reg  (verified m89/m91)
  const int r0  = row0 + wr + ((lane >> 4) << 2);
  const int c0g = col0 + wc + (lane & 15);
  float bv[4];
#pragma unroll
  for (int j = 0; j < 4; ++j) bv[j] = bias[c0g + j * 16];
#pragma unroll
  for (int i = 0; i < 4; ++i)
#pragma unroll
    for (int j = 0; j < 4; ++j)
#pragma unroll
      for (int r = 0; r < 4; ++r) {
        const int m = r0 + i * 16 + r;
        const int n = c0g + j * 16;
        dout[(size_t)m * D_N + n] = tanhf(acc[i][j][r] + bv[j]);
      }
}

extern "C" void kernel_launch(void* const* d_in, const int* in_sizes, int n_in,
                              void* d_out, int out_size, void* d_ws, size_t ws_size,
                              hipStream_t stream) {
  const float* outp = (const float*)d_in[0];
  const float* ctx  = (const float*)d_in[1];
  const float* W    = (const float*)d_in[2];
  const float* bias = (const float*)d_in[3];
  float* dout = (float*)d_out;
  hipLaunchKernelGGL(hardattn_fused, dim3(GEMM_BLOCKS + FILL_BLOCKS), dim3(NTHREADS),
                     0, stream, outp, ctx, W, bias, dout);
}